// Round 1
// baseline (112.997 us; speedup 1.0000x reference)
//
#include <hip/hip_runtime.h>
#include <math.h>

#define F_IN 256
#define NTREES 512
#define DEPTH 6
#define NCOLS (NTREES * DEPTH)   /* 3072 */
#define BATCH 512
#define OUTW (NTREES * 3)        /* 1536 */

// ---------------------------------------------------------------------------
// Kernel 1: exact 1.5-entmax along axis 0 (F=256) for each of 3072 columns.
// One 256-thread block per column: bitonic sort (descending) + inclusive scan
// of zs and zs^2 in LDS, then tau_star lookup and sparse-weight write.
// ---------------------------------------------------------------------------
__global__ __launch_bounds__(256) void k_entmax(const float* __restrict__ att,
                                                float* __restrict__ cw) {
    const int n = blockIdx.x;
    const int tid = threadIdx.x;
    __shared__ float s_zs[F_IN];
    __shared__ float s_c1[F_IN];
    __shared__ float s_c2[F_IN];
    __shared__ int s_cnt;

    float z = att[tid * NCOLS + n] * 0.5f;

    // column max via LDS tree reduction (scratch: s_c1)
    s_c1[tid] = z;
    __syncthreads();
    for (int s = 128; s >= 1; s >>= 1) {
        if (tid < s) s_c1[tid] = fmaxf(s_c1[tid], s_c1[tid + s]);
        __syncthreads();
    }
    z -= s_c1[0];
    __syncthreads();

    s_zs[tid] = z;
    __syncthreads();

    // bitonic sort, descending
    for (int k = 2; k <= F_IN; k <<= 1) {
        for (int j = k >> 1; j > 0; j >>= 1) {
            int partner = tid ^ j;
            float a = s_zs[tid];
            float b = s_zs[partner];
            bool desc = ((tid & k) == 0);
            float keep;
            if (partner > tid) keep = desc ? fmaxf(a, b) : fminf(a, b);
            else               keep = desc ? fminf(a, b) : fmaxf(a, b);
            __syncthreads();
            s_zs[tid] = keep;
            __syncthreads();
        }
    }
    float zs = s_zs[tid];

    // inclusive scans of zs and zs^2 (Hillis-Steele)
    s_c1[tid] = zs;
    s_c2[tid] = zs * zs;
    __syncthreads();
    for (int off = 1; off < F_IN; off <<= 1) {
        float a1 = s_c1[tid], a2 = s_c2[tid];
        float b1 = 0.f, b2 = 0.f;
        if (tid >= off) { b1 = s_c1[tid - off]; b2 = s_c2[tid - off]; }
        __syncthreads();
        s_c1[tid] = a1 + b1;
        s_c2[tid] = a2 + b2;
        __syncthreads();
    }

    float rho    = (float)(tid + 1);
    float mean   = s_c1[tid] / rho;
    float meansq = s_c2[tid] / rho;
    float ss     = rho * (meansq - mean * mean);
    float delta  = (1.f - ss) / rho;
    float tau    = mean - sqrtf(fmaxf(delta, 0.f));
    int   flag   = (tau <= zs) ? 1 : 0;

    s_c1[tid] = tau;            // own-element overwrite; no cross-read before barrier
    if (tid == 0) s_cnt = 0;
    __syncthreads();
    unsigned long long m = __ballot(flag);
    if ((tid & 63) == 0) atomicAdd(&s_cnt, __popcll(m));
    __syncthreads();

    int k = s_cnt - 1;
    float tau_star = s_c1[k];
    float v = fmaxf(z - tau_star, 0.f);
    cw[tid * NCOLS + n] = v * v;
}

// ---------------------------------------------------------------------------
// Kernel 2: fv[n][b] = sum_f cw[f][n] * input[b][f]   (fp32, 64x64 LDS tile)
// Output stored transposed [N=3072][B=512] so kernel 3 reads coalesced in b.
// ---------------------------------------------------------------------------
__global__ __launch_bounds__(256) void k_gemm(const float* __restrict__ cw,
                                              const float* __restrict__ inp,
                                              float* __restrict__ fv) {
    const int n0 = blockIdx.x * 64;
    const int b0 = blockIdx.y * 64;
    const int tid = threadIdx.x;
    __shared__ float sA[16][64];   // cw[f][n] tile
    __shared__ float sB[16][68];   // input[b][f] tile, transposed; stride 68: 16B-aligned rows
    const int tx = tid & 15, ty = tid >> 4;
    const int a_k = tid >> 4, a_n = (tid & 15) * 4;
    const int b_b = tid >> 2, b_k = (tid & 3) * 4;
    float acc[4][4] = {};
    for (int f0 = 0; f0 < F_IN; f0 += 16) {
        float4 av = *(const float4*)&cw[(f0 + a_k) * NCOLS + n0 + a_n];
        float4 bv = *(const float4*)&inp[(b0 + b_b) * F_IN + f0 + b_k];
        __syncthreads();
        *(float4*)&sA[a_k][a_n] = av;
        sB[b_k + 0][b_b] = bv.x;
        sB[b_k + 1][b_b] = bv.y;
        sB[b_k + 2][b_b] = bv.z;
        sB[b_k + 3][b_b] = bv.w;
        __syncthreads();
#pragma unroll
        for (int kk = 0; kk < 16; ++kk) {
            float a[4], b[4];
#pragma unroll
            for (int i = 0; i < 4; ++i) a[i] = sA[kk][ty * 4 + i];
#pragma unroll
            for (int j = 0; j < 4; ++j) b[j] = sB[kk][tx * 4 + j];
#pragma unroll
            for (int i = 0; i < 4; ++i)
#pragma unroll
                for (int j = 0; j < 4; ++j)
                    acc[i][j] = fmaf(a[i], b[j], acc[i][j]);
        }
    }
#pragma unroll
    for (int i = 0; i < 4; ++i) {
        float4 v = make_float4(acc[i][0], acc[i][1], acc[i][2], acc[i][3]);
        *(float4*)&fv[(n0 + ty * 4 + i) * BATCH + b0 + tx * 4] = v;
    }
}

// ---------------------------------------------------------------------------
// Kernel 3: soft binning + DP leaf-product + response contraction.
// Block = 8 trees x 64 batch rows; output staged via LDS for coalesced writes.
// ---------------------------------------------------------------------------
__global__ __launch_bounds__(256) void k_tree(const float* __restrict__ fv,
                                              const float* __restrict__ thr,
                                              const float* __restrict__ ltemp,
                                              const float* __restrict__ resp,
                                              float* __restrict__ out) {
    const int t0 = blockIdx.x * 8;
    const int b0 = blockIdx.y * 64;
    const int tid = threadIdx.x;
    const int bl = tid & 63;
    const int b = b0 + bl;
    const int tsub = tid >> 6;                 // 0..3 (one wave per tsub)
    __shared__ float s_resp[8 * 192];
    __shared__ float s_out[64][25];            // 25: break 24-stride bank conflicts

    for (int i = tid; i < 8 * 192; i += 256)
        s_resp[i] = resp[t0 * 192 + i];
    __syncthreads();

#pragma unroll
    for (int half_t = 0; half_t < 2; ++half_t) {
        const int ttl = tsub + half_t * 4;
        const int tt = t0 + ttl;
        float bpos[6], bneg[6];
#pragma unroll
        for (int d = 0; d < 6; ++d) {
            float fvv = fv[(tt * 6 + d) * BATCH + b];
            float tl = (fvv - thr[tt * 6 + d]) * expf(-ltemp[tt * 6 + d]);
            float hp = 0.5f * tl + 0.5f;
            float hn = 0.5f - 0.5f * tl;
            bpos[d] = fminf(fmaxf(hp, -0.5f), 1.5f);   // bit d == 0
            bneg[d] = fminf(fmaxf(hn, -0.5f), 1.5f);   // bit d == 1
        }
        // DP over depths: p[c] = prod_d (bit_d(c) ? bneg[d] : bpos[d])
        float p[64];
        p[0] = 1.f;
#pragma unroll
        for (int d = 0; d < 6; ++d) {
            int half = 1 << d;
#pragma unroll 32
            for (int i = half - 1; i >= 0; --i) {
                float v = p[i];
                p[i + half] = v * bneg[d];
                p[i]        = v * bpos[d];
            }
        }
        float a0 = 0.f, a1 = 0.f, a2 = 0.f;
        const float* r = &s_resp[ttl * 192];
#pragma unroll
        for (int c = 0; c < 64; ++c) {
            a0 = fmaf(p[c], r[c], a0);
            a1 = fmaf(p[c], r[64 + c], a1);
            a2 = fmaf(p[c], r[128 + c], a2);
        }
        s_out[bl][ttl * 3 + 0] = a0;
        s_out[bl][ttl * 3 + 1] = a1;
        s_out[bl][ttl * 3 + 2] = a2;
    }
    __syncthreads();
    for (int i = tid; i < 64 * 24; i += 256) {
        int row = i / 24, col = i % 24;
        out[(b0 + row) * OUTW + t0 * 3 + col] = s_out[row][col];
    }
}

extern "C" void kernel_launch(void* const* d_in, const int* in_sizes, int n_in,
                              void* d_out, int out_size, void* d_ws, size_t ws_size,
                              hipStream_t stream) {
    const float* input = (const float*)d_in[0];   // [512, 256]
    const float* att   = (const float*)d_in[1];   // [256, 3072]
    const float* thr   = (const float*)d_in[2];   // [512, 6]
    const float* ltemp = (const float*)d_in[3];   // [512, 6]
    const float* resp  = (const float*)d_in[4];   // [512, 3, 64]
    float* out = (float*)d_out;                   // [512, 1536]

    float* cw = (float*)d_ws;                     // [256, 3072]  3 MB
    float* fv = cw + F_IN * NCOLS;                // [3072, 512]  6 MB

    hipLaunchKernelGGL(k_entmax, dim3(NCOLS), dim3(256), 0, stream, att, cw);
    hipLaunchKernelGGL(k_gemm, dim3(NCOLS / 64, BATCH / 64), dim3(256), 0, stream,
                       cw, input, fv);
    hipLaunchKernelGGL(k_tree, dim3(NTREES / 8, BATCH / 64), dim3(256), 0, stream,
                       fv, thr, ltemp, resp, out);
}

// Round 2
// 98.390 us; speedup vs baseline: 1.1485x; 1.1485x over previous
//
#include <hip/hip_runtime.h>
#include <math.h>

#define F_IN 256
#define NTREES 512
#define DEPTH 6
#define NCOLS (NTREES * DEPTH)   /* 3072 */
#define BATCH 512
#define OUTW (NTREES * 3)        /* 1536 */

// ---------------------------------------------------------------------------
// Kernel 1: exact 1.5-entmax along axis 0 (F=256) for each of 3072 columns.
// Newton root-solve of f(tau) = sum max(z-tau,0)^2 - 1 (convex, decreasing:
// monotone quadratic convergence from tau0 = zmax-1). One wave per column,
// 4 elements/lane in registers, 4 columns in flight per wave for ILP.
// LDS-transposed staging for coalesced global load and store.
// ---------------------------------------------------------------------------
__global__ __launch_bounds__(256) void k_entmax(const float* __restrict__ att,
                                                float* __restrict__ cw) {
    const int n0 = blockIdx.x * 16;
    const int tid = threadIdx.x;
    const int lane = tid & 63;
    const int w = tid >> 6;                 // wave id 0..3
    __shared__ float s_z[16][260];          // stride 260 words: 16B-aligned rows, no 4+-way conflicts

    // coalesced load: 16 columns x 256 rows, transposed into LDS
    const int cld = tid & 15;
#pragma unroll
    for (int it = 0; it < 16; ++it) {
        int f = (tid >> 4) + it * 16;
        s_z[cld][f] = att[f * NCOLS + n0 + cld];
    }
    __syncthreads();

    // each wave owns 4 columns; 4 in flight for shfl-latency hiding
    float4 z[4];
    float m[4], tau[4];
#pragma unroll
    for (int c = 0; c < 4; ++c) {
        float4 v = *(const float4*)&s_z[w * 4 + c][4 * lane];
        z[c] = make_float4(v.x * 0.5f, v.y * 0.5f, v.z * 0.5f, v.w * 0.5f);
        m[c] = fmaxf(fmaxf(z[c].x, z[c].y), fmaxf(z[c].z, z[c].w));
    }
#pragma unroll
    for (int off = 32; off >= 1; off >>= 1)
#pragma unroll
        for (int c = 0; c < 4; ++c)
            m[c] = fmaxf(m[c], __shfl_xor(m[c], off));
#pragma unroll
    for (int c = 0; c < 4; ++c) {
        z[c].x -= m[c]; z[c].y -= m[c]; z[c].z -= m[c]; z[c].w -= m[c];
        tau[c] = -1.0f;                     // f(zmax-1) >= 0 guaranteed
    }

    for (int iter = 0; iter < 14; ++iter) {
        float S1[4], S2[4];
#pragma unroll
        for (int c = 0; c < 4; ++c) {
            float d0 = fmaxf(z[c].x - tau[c], 0.f);
            float d1 = fmaxf(z[c].y - tau[c], 0.f);
            float d2 = fmaxf(z[c].z - tau[c], 0.f);
            float d3 = fmaxf(z[c].w - tau[c], 0.f);
            S1[c] = (d0 + d1) + (d2 + d3);
            S2[c] = fmaf(d0, d0, fmaf(d1, d1, fmaf(d2, d2, d3 * d3)));
        }
#pragma unroll
        for (int off = 32; off >= 1; off >>= 1)
#pragma unroll
            for (int c = 0; c < 4; ++c) {
                S1[c] += __shfl_xor(S1[c], off);
                S2[c] += __shfl_xor(S2[c], off);
            }
        bool done = true;
#pragma unroll
        for (int c = 0; c < 4; ++c) {
            tau[c] += (S2[c] - 1.f) / (2.f * S1[c]);   // Newton; S1 >= 1 near root
            done = done && (fabsf(S2[c] - 1.f) < 4e-6f);
        }
        if (done) break;                    // wave-uniform (reduced values)
    }

    // p = clip(z - tau, 0)^2, back through LDS for coalesced global store
#pragma unroll
    for (int c = 0; c < 4; ++c) {
        float4 pv;
        float v0 = fmaxf(z[c].x - tau[c], 0.f);
        float v1 = fmaxf(z[c].y - tau[c], 0.f);
        float v2 = fmaxf(z[c].z - tau[c], 0.f);
        float v3 = fmaxf(z[c].w - tau[c], 0.f);
        pv.x = v0 * v0; pv.y = v1 * v1; pv.z = v2 * v2; pv.w = v3 * v3;
        *(float4*)&s_z[w * 4 + c][4 * lane] = pv;
    }
    __syncthreads();
#pragma unroll
    for (int it = 0; it < 16; ++it) {
        int f = (tid >> 4) + it * 16;
        cw[f * NCOLS + n0 + cld] = s_z[cld][f];
    }
}

// ---------------------------------------------------------------------------
// Kernel 2: fv[n][b] = sum_f cw[f][n] * input[b][f]   (fp32, 64x64 LDS tile)
// Output stored transposed [N=3072][B=512] so kernel 3 reads coalesced in b.
// ---------------------------------------------------------------------------
__global__ __launch_bounds__(256) void k_gemm(const float* __restrict__ cw,
                                              const float* __restrict__ inp,
                                              float* __restrict__ fv) {
    const int n0 = blockIdx.x * 64;
    const int b0 = blockIdx.y * 64;
    const int tid = threadIdx.x;
    __shared__ float sA[16][64];   // cw[f][n] tile
    __shared__ float sB[16][68];   // input[b][f] tile, transposed; stride 68: 16B-aligned rows
    const int tx = tid & 15, ty = tid >> 4;
    const int a_k = tid >> 4, a_n = (tid & 15) * 4;
    const int b_b = tid >> 2, b_k = (tid & 3) * 4;
    float acc[4][4] = {};
    for (int f0 = 0; f0 < F_IN; f0 += 16) {
        float4 av = *(const float4*)&cw[(f0 + a_k) * NCOLS + n0 + a_n];
        float4 bv = *(const float4*)&inp[(b0 + b_b) * F_IN + f0 + b_k];
        __syncthreads();
        *(float4*)&sA[a_k][a_n] = av;
        sB[b_k + 0][b_b] = bv.x;
        sB[b_k + 1][b_b] = bv.y;
        sB[b_k + 2][b_b] = bv.z;
        sB[b_k + 3][b_b] = bv.w;
        __syncthreads();
#pragma unroll
        for (int kk = 0; kk < 16; ++kk) {
            float a[4], b[4];
#pragma unroll
            for (int i = 0; i < 4; ++i) a[i] = sA[kk][ty * 4 + i];
#pragma unroll
            for (int j = 0; j < 4; ++j) b[j] = sB[kk][tx * 4 + j];
#pragma unroll
            for (int i = 0; i < 4; ++i)
#pragma unroll
                for (int j = 0; j < 4; ++j)
                    acc[i][j] = fmaf(a[i], b[j], acc[i][j]);
        }
    }
#pragma unroll
    for (int i = 0; i < 4; ++i) {
        float4 v = make_float4(acc[i][0], acc[i][1], acc[i][2], acc[i][3]);
        *(float4*)&fv[(n0 + ty * 4 + i) * BATCH + b0 + tx * 4] = v;
    }
}

// ---------------------------------------------------------------------------
// Kernel 3: soft binning + DP leaf-product + response contraction.
// Block = 8 trees x 64 batch rows; output staged via LDS for coalesced writes.
// ---------------------------------------------------------------------------
__global__ __launch_bounds__(256) void k_tree(const float* __restrict__ fv,
                                              const float* __restrict__ thr,
                                              const float* __restrict__ ltemp,
                                              const float* __restrict__ resp,
                                              float* __restrict__ out) {
    const int t0 = blockIdx.x * 8;
    const int b0 = blockIdx.y * 64;
    const int tid = threadIdx.x;
    const int bl = tid & 63;
    const int b = b0 + bl;
    const int tsub = tid >> 6;                 // 0..3 (one wave per tsub)
    __shared__ float s_resp[8 * 192];
    __shared__ float s_out[64][25];            // 25: break 24-stride bank conflicts

    for (int i = tid; i < 8 * 192; i += 256)
        s_resp[i] = resp[t0 * 192 + i];
    __syncthreads();

#pragma unroll
    for (int half_t = 0; half_t < 2; ++half_t) {
        const int ttl = tsub + half_t * 4;
        const int tt = t0 + ttl;
        float bpos[6], bneg[6];
#pragma unroll
        for (int d = 0; d < 6; ++d) {
            float fvv = fv[(tt * 6 + d) * BATCH + b];
            float tl = (fvv - thr[tt * 6 + d]) * expf(-ltemp[tt * 6 + d]);
            float hp = 0.5f * tl + 0.5f;
            float hn = 0.5f - 0.5f * tl;
            bpos[d] = fminf(fmaxf(hp, -0.5f), 1.5f);   // bit d == 0
            bneg[d] = fminf(fmaxf(hn, -0.5f), 1.5f);   // bit d == 1
        }
        // DP over depths: p[c] = prod_d (bit_d(c) ? bneg[d] : bpos[d])
        float p[64];
        p[0] = 1.f;
#pragma unroll
        for (int d = 0; d < 6; ++d) {
            int half = 1 << d;
#pragma unroll 32
            for (int i = half - 1; i >= 0; --i) {
                float v = p[i];
                p[i + half] = v * bneg[d];
                p[i]        = v * bpos[d];
            }
        }
        float a0 = 0.f, a1 = 0.f, a2 = 0.f;
        const float* r = &s_resp[ttl * 192];
#pragma unroll
        for (int c = 0; c < 64; ++c) {
            a0 = fmaf(p[c], r[c], a0);
            a1 = fmaf(p[c], r[64 + c], a1);
            a2 = fmaf(p[c], r[128 + c], a2);
        }
        s_out[bl][ttl * 3 + 0] = a0;
        s_out[bl][ttl * 3 + 1] = a1;
        s_out[bl][ttl * 3 + 2] = a2;
    }
    __syncthreads();
    for (int i = tid; i < 64 * 24; i += 256) {
        int row = i / 24, col = i % 24;
        out[(b0 + row) * OUTW + t0 * 3 + col] = s_out[row][col];
    }
}

extern "C" void kernel_launch(void* const* d_in, const int* in_sizes, int n_in,
                              void* d_out, int out_size, void* d_ws, size_t ws_size,
                              hipStream_t stream) {
    const float* input = (const float*)d_in[0];   // [512, 256]
    const float* att   = (const float*)d_in[1];   // [256, 3072]
    const float* thr   = (const float*)d_in[2];   // [512, 6]
    const float* ltemp = (const float*)d_in[3];   // [512, 6]
    const float* resp  = (const float*)d_in[4];   // [512, 3, 64]
    float* out = (float*)d_out;                   // [512, 1536]

    float* cw = (float*)d_ws;                     // [256, 3072]  3 MB
    float* fv = cw + F_IN * NCOLS;                // [3072, 512]  6 MB

    hipLaunchKernelGGL(k_entmax, dim3(NCOLS / 16), dim3(256), 0, stream, att, cw);
    hipLaunchKernelGGL(k_gemm, dim3(NCOLS / 64, BATCH / 64), dim3(256), 0, stream,
                       cw, input, fv);
    hipLaunchKernelGGL(k_tree, dim3(NTREES / 8, BATCH / 64), dim3(256), 0, stream,
                       fv, thr, ltemp, resp, out);
}